// Round 16
// baseline (857.266 us; speedup 1.0000x reference)
//
#include <hip/hip_runtime.h>
#include <hip/hip_bf16.h>
#include <hip/hip_cooperative_groups.h>
#include <math.h>

namespace cg = cooperative_groups;

// SigmaMoE R23: T=4096, H=1024, I=512, E=16, top-2, IS=1024.
// R15 post-mortem: XCD swizzle +1.5us (264.5 best). Budget: visible kernels
// ~160us, total 264.5 -> ~100us is inter-dispatch overhead (matches R1's
// ~11-16us/dispatch). All in-kernel levers at measured local optima.
// This round: ONE cooperative mega-kernel (hipLaunchCooperativeKernel is
// harness-supported): {zero cnt -> sync -> prep -> sync -> gateup -> sync ->
// down -> sync -> final}, phase bodies byte-identical to R22 as grid-stride
// virtual-block loops. Grid from occupancy query (co-residency guaranteed by
// the API — not R13's hand-rolled spin). Deletes memset dispatch too.
#define H_DIM 1024
#define I_DIM 512
#define E_NUM 16
#define T_TOK 4096
#define IS_DIM 1024
#define CSTR 32       // cnt stride in ints (128B = own cache line per expert)

// prep virtual-block ranges: router, then ALL weight transposes.
#define P_RT   1024               // router blocks (4 tokens each)
#define P_WU   (P_RT + 2048)      // wg transpose
#define P_SG   (P_WU + 2048)      // wu transpose
#define P_SU   (P_SG + 256)       // sg transpose
#define P_WD   (P_SU + 256)       // su transpose
#define P_SD   (P_WD + 2048)      // wd transpose
#define P_END  (P_SD + 256)       // sd transpose

#define G_GEMM 1152               // gateup: 512 shared + <=640 routed
#define D_GRID 896                // down: 256 shared + <=640 routed

typedef unsigned short u16;
typedef __attribute__((ext_vector_type(8))) short short8;   // 8 x bf16 (16B)
typedef __attribute__((ext_vector_type(4))) float floatx4;  // 16x16 acc

__device__ __forceinline__ float bf2f(u16 u) {
    union { unsigned int u; float f; } c; c.u = ((unsigned int)u) << 16; return c.f;
}
__device__ __forceinline__ u16 f2bf(float f) {
    union { __hip_bfloat16 b; u16 u; } c;
    c.b = __float2bfloat16(f);
    return c.u;
}
// async global->LDS, 16B/lane; LDS dest = wave-uniform base + lane*16.
__device__ __forceinline__ void gld16(const u16* g, u16* l) {
    __builtin_amdgcn_global_load_lds(
        (const __attribute__((address_space(1))) unsigned int*)g,
        (__attribute__((address_space(3))) unsigned int*)l, 16, 0, 0);
}

// ---------------------------------------------------------------------------
// 64x64 convert+transpose tile (R18): f32 K-major -> bf16 N-major.
// tile = 64 x 72 u16, swizzle (r,c) -> tile[r*72 + (((c>>4)^(r>>4))<<4)+(c&15)]
// writes 2x short8, reads conflict-free.
// ---------------------------------------------------------------------------
__device__ __forceinline__ void tr64(const float* src, u16* dst, int R, int C,
                                     int local, u16* tile)
{
    int tpm = (R >> 6) * (C >> 6);
    int mat = local / tpm;
    int tl_ = local - mat * tpm;
    int tcn = C >> 6;
    int tr = tl_ / tcn, tc = tl_ - tr * tcn;
    src += (size_t)mat * R * C;
    dst += (size_t)mat * R * C;
    int t = threadIdx.x;
    int r0 = t >> 2, g0 = t & 3;
    const float* sp = src + (size_t)(tr * 64 + r0) * C + tc * 64 + (g0 << 4);
    u16 cv[16];
    #pragma unroll
    for (int j = 0; j < 16; j += 4) {
        float4 v = *(const float4*)(sp + j);
        cv[j + 0] = f2bf(v.x);
        cv[j + 1] = f2bf(v.y);
        cv[j + 2] = f2bf(v.z);
        cv[j + 3] = f2bf(v.w);
    }
    u16* tp = tile + r0 * 72 + ((g0 ^ (r0 >> 4)) << 4);
    *(short8*)(tp)     = *(const short8*)(cv);
    *(short8*)(tp + 8) = *(const short8*)(cv + 8);
    __syncthreads();
    int cW = t >> 2, rW = (t & 3) << 4;
    int rb = (((cW >> 4) ^ (t & 3)) << 4) + (cW & 15);
    u16 tmp[16];
    #pragma unroll
    for (int j = 0; j < 16; ++j) tmp[j] = tile[(rW + j) * 72 + rb];
    u16* dp = dst + (size_t)(tc * 64 + cW) * R + tr * 64 + rW;
    *(uint4*)(dp)     = *(const uint4*)(tmp);
    *(uint4*)(dp + 8) = *(const uint4*)(tmp + 8);
}

// ---------------------------------------------------------------------------
// Map a routed block index to (expert, m-tile, sub-tile, act row base).
// ---------------------------------------------------------------------------
__device__ __forceinline__ int derive_routed(int gi, const int* cnt,
                                             int& e, int& mt, int& sub, int& abase)
{
    int off = 0, b = 0;
    #pragma unroll
    for (int ee = 0; ee < E_NUM; ++ee) {
        int mts = (cnt[ee * CSTR] + 127) >> 7;
        int span = mts << 3;
        if (gi < off + span) {
            int local = gi - off;
            e = ee; mt = local >> 3; sub = local & 7; abase = b;
            return 1;
        }
        off += span; b += mts << 7;
    }
    return 0;
}

// ---------------------------------------------------------------------------
// prep virtual block: router (+ xb emission) or one weight-transpose tile.
// ---------------------------------------------------------------------------
__device__ __forceinline__ void prep_vb(int bi, u16* tile,
            const float* x, const float* rw,
            const float* wg, const float* wu, const float* sg, const float* su,
            const float* wd, const float* sd,
            u16* wgt, u16* wut, u16* sgt, u16* sut, u16* wdt, u16* sdt,
            u16* xb, float* topkw, int* elist, int* cnt)
{
    if (bi >= P_RT) {
        if (bi < P_WU)      tr64(wg, wgt, 1024, 512,  bi - P_RT, tile);
        else if (bi < P_SG) tr64(wu, wut, 1024, 512,  bi - P_WU, tile);
        else if (bi < P_SU) tr64(sg, sgt, 1024, 1024, bi - P_SG, tile);
        else if (bi < P_WD) tr64(su, sut, 1024, 1024, bi - P_SU, tile);
        else if (bi < P_SD) tr64(wd, wdt, 512, 1024,  bi - P_WD, tile);
        else                tr64(sd, sdt, 1024, 1024, bi - P_SD, tile);
        return;
    }
    // ---- router + x->bf16 (4 tokens per virtual block, 1 wave each) ----
    int lane = threadIdx.x & 63;
    int wv = threadIdx.x >> 6;
    int t = bi * 4 + wv;
    const float* xr = x + (size_t)t * H_DIM;
    float xv[16];
    #pragma unroll
    for (int j = 0; j < 16; ++j) xv[j] = xr[j * 64 + lane];
    u16* xrow = xb + (size_t)t * H_DIM;
    #pragma unroll
    for (int j = 0; j < 16; ++j) xrow[j * 64 + lane] = f2bf(xv[j]);
    float sc[E_NUM];
    #pragma unroll
    for (int e = 0; e < E_NUM; ++e) sc[e] = 0.f;
    #pragma unroll
    for (int e = 0; e < E_NUM; ++e) {
        const float* rr = rw + e * H_DIM;
        #pragma unroll
        for (int j = 0; j < 16; ++j) sc[e] += xv[j] * rr[j * 64 + lane];
    }
    #pragma unroll
    for (int off = 32; off > 0; off >>= 1) {
        float tmp[E_NUM];
        #pragma unroll
        for (int e = 0; e < E_NUM; ++e) tmp[e] = __shfl_xor(sc[e], off, 64);
        #pragma unroll
        for (int e = 0; e < E_NUM; ++e) sc[e] += tmp[e];
    }
    if (lane == 0) {
        float b1 = -1e30f, b2 = -1e30f; int i1 = 0, i2 = 0;
        #pragma unroll
        for (int e = 0; e < E_NUM; ++e) {
            if (sc[e] > b1) { b2 = b1; i2 = i1; b1 = sc[e]; i1 = e; }
            else if (sc[e] > b2) { b2 = sc[e]; i2 = e; }
        }
        float w1 = 1.f / (1.f + __expf(b2 - b1));
        float w2 = 1.f - w1;
        topkw[t * 2]     = w1;
        topkw[t * 2 + 1] = w2;
        int p1 = atomicAdd(&cnt[i1 * CSTR], 1); elist[i1 * T_TOK + p1] = (t << 1);
        int p2 = atomicAdd(&cnt[i2 * CSTR], 1); elist[i2 * T_TOK + p2] = (t << 1) | 1;
    }
}

// ---------------------------------------------------------------------------
// gateup virtual block: 128 rows x (64 g + 64 u), BK=64, 2-phase, 32KB LDS.
// ---------------------------------------------------------------------------
__device__ __forceinline__ void gateup_vb(int bi, u16* smem,
            const u16* xb, const u16* wgt, const u16* wut,
            const u16* sgt, const u16* sut,
            const int* elist, const int* cnt,
            u16* act, u16* sact)
{
    int kind, e = 0, mt, cb, abase = 0;
    if (bi < 512) { kind = 1; mt = bi >> 4; cb = bi & 15; }
    else {
        kind = 0;
        if (!derive_routed(bi - 512, cnt, e, mt, cb, abase)) return;
    }

    u16* lA = smem;              // [2 chunks][8 calls][512] = 128x64
    u16* lG = smem + 8192;       // [2][4][512] = 64x64
    u16* lU = smem + 12288;
    int tid = threadIdx.x, lane = tid & 63, w = tid >> 6;
    int srow = lane >> 2, scp = lane & 3;

    const u16* gb = kind ? sgt : (wgt + (size_t)e * I_DIM * H_DIM);
    const u16* ub = kind ? sut : (wut + (size_t)e * I_DIM * H_DIM);
    int c = cnt[e * CSTR];

    const u16 *gA[2], *gG, *gU;
    u16 *dA[2], *dG, *dU;
    #pragma unroll
    for (int jj = 0; jj < 2; ++jj) {
        int call = w * 2 + jj;
        int row = call * 16 + srow;               // 0..127
        int gc = scp ^ ((row >> 1) & 3);
        int tok;
        if (kind) tok = mt * 128 + row;
        else {
            int p = mt * 128 + row;
            int pc = p < c ? p : c - 1;
            tok = elist[e * T_TOK + pc] >> 1;
        }
        gA[jj] = xb + (size_t)tok * H_DIM + gc * 8;
        dA[jj] = lA + call * 512;
    }
    {
        int row = w * 16 + srow;                  // 0..63
        int gc = scp ^ ((row >> 1) & 3);
        gG = gb + (size_t)(cb * 64 + row) * H_DIM + gc * 8;
        gU = ub + (size_t)(cb * 64 + row) * H_DIM + gc * 8;
        dG = lG + w * 512;
        dU = lU + w * 512;
    }

    int wr = w >> 1, wc = w & 1;
    int quad = lane >> 4, l15 = lane & 15;
    const u16 *fA[4], *fG[2], *fU[2];
    #pragma unroll
    for (int i = 0; i < 4; ++i) {
        int r = wr * 64 + i * 16 + l15;
        fA[i] = lA + r * 32 + (quad ^ ((r >> 1) & 3)) * 8;
    }
    #pragma unroll
    for (int j = 0; j < 2; ++j) {
        int n = wc * 32 + j * 16 + l15;
        fG[j] = lG + n * 32 + (quad ^ ((n >> 1) & 3)) * 8;
        fU[j] = lU + n * 32 + (quad ^ ((n >> 1) & 3)) * 8;
    }

    floatx4 accg[4][2], accu[4][2];
    #pragma unroll
    for (int i = 0; i < 4; ++i)
        #pragma unroll
        for (int j = 0; j < 2; ++j)
            #pragma unroll
            for (int r = 0; r < 4; ++r) { accg[i][j][r] = 0.f; accu[i][j][r] = 0.f; }

    for (int s = 0; s < H_DIM / 64; ++s) {
        #pragma unroll
        for (int q = 0; q < 2; ++q) {
            gld16(gA[0] + q * 32, dA[0] + q * 4096);
            gld16(gA[1] + q * 32, dA[1] + q * 4096);
            gld16(gG + q * 32, dG + q * 2048);
            gld16(gU + q * 32, dU + q * 2048);
        }
        gA[0] += 64; gA[1] += 64; gG += 64; gU += 64;
        __syncthreads();
        #pragma unroll
        for (int q = 0; q < 2; ++q) {
            short8 a[4], g[2], u[2];
            #pragma unroll
            for (int i = 0; i < 4; ++i) a[i] = *(const short8*)(fA[i] + q * 4096);
            #pragma unroll
            for (int j = 0; j < 2; ++j) {
                g[j] = *(const short8*)(fG[j] + q * 2048);
                u[j] = *(const short8*)(fU[j] + q * 2048);
            }
            #pragma unroll
            for (int i = 0; i < 4; ++i)
                #pragma unroll
                for (int j = 0; j < 2; ++j) {
                    accg[i][j] = __builtin_amdgcn_mfma_f32_16x16x32_bf16(a[i], g[j], accg[i][j], 0, 0, 0);
                    accu[i][j] = __builtin_amdgcn_mfma_f32_16x16x32_bf16(a[i], u[j], accu[i][j], 0, 0, 0);
                }
        }
        __syncthreads();
    }

    u16* obase = kind ? (sact + (size_t)(mt * 128) * IS_DIM)
                      : (act + (size_t)(abase + mt * 128) * I_DIM);
    int old = kind ? IS_DIM : I_DIM;
    #pragma unroll
    for (int i = 0; i < 4; ++i)
        #pragma unroll
        for (int j = 0; j < 2; ++j)
            #pragma unroll
            for (int r = 0; r < 4; ++r) {
                int row = wr * 64 + i * 16 + quad * 4 + r;
                int col = cb * 64 + wc * 32 + j * 16 + l15;
                float gg = accg[i][j][r], uu = accu[i][j][r];
                float aa = gg / (1.f + __expf(-gg)) * uu;   // silu(g)*u
                obase[(size_t)row * old + col] = f2bf(aa);
            }
}

// ---------------------------------------------------------------------------
// down virtual block: 128 x 128, BK=64, 2-phase, 32KB LDS.
// Routed K=512 -> y0/y1 scatter; shared K=1024 -> f32 out.
// ---------------------------------------------------------------------------
__device__ __forceinline__ void down_vb(int bi, u16* smem,
            const u16* act, const u16* sact, const u16* wdt, const u16* sdt,
            const int* elist, const int* cnt, const float* topkw,
            u16* y0, u16* y1, float* out)
{
    int kind, e = 0, mt, nb, abase = 0;
    if (bi < 256) { kind = 1; mt = bi >> 3; nb = bi & 7; }     // 32 mts x 8 nbs
    else {
        kind = 0;
        if (!derive_routed(bi - 256, cnt, e, mt, nb, abase)) return;
    }

    u16* lA = smem;              // [2][8][512] = 128 x 64
    u16* lB = smem + 8192;       // [2][8][512] = 128 x 64 (B rows = out cols)
    int tid = threadIdx.x, lane = tid & 63, w = tid >> 6;
    int srow = lane >> 2, scp = lane & 3;

    int K = kind ? IS_DIM : I_DIM;
    const u16* ab = kind ? (sact + (size_t)(mt * 128) * IS_DIM)
                         : (act + (size_t)(abase + mt * 128) * I_DIM);
    const u16* bb = kind ? (sdt + (size_t)(nb * 128) * IS_DIM)
                         : (wdt + ((size_t)e * H_DIM + nb * 128) * I_DIM);
    int c = cnt[e * CSTR];

    const u16 *gA[2], *gB[2];
    u16 *dA[2], *dB[2];
    #pragma unroll
    for (int jj = 0; jj < 2; ++jj) {
        int call = w * 2 + jj;
        int row = call * 16 + srow;               // 0..127
        int gc = scp ^ ((row >> 1) & 3);
        gA[jj] = ab + (size_t)row * K + gc * 8;
        dA[jj] = lA + call * 512;
        gB[jj] = bb + (size_t)row * K + gc * 8;
        dB[jj] = lB + call * 512;
    }

    int wr = w >> 1, wc = w & 1;
    int quad = lane >> 4, l15 = lane & 15;
    const u16 *fA[4], *fB[4];
    #pragma unroll
    for (int i = 0; i < 4; ++i) {
        int r = wr * 64 + i * 16 + l15;
        fA[i] = lA + r * 32 + (quad ^ ((r >> 1) & 3)) * 8;
    }
    #pragma unroll
    for (int j = 0; j < 4; ++j) {
        int n = wc * 64 + j * 16 + l15;
        fB[j] = lB + n * 32 + (quad ^ ((n >> 1) & 3)) * 8;
    }

    floatx4 acc[4][4];
    #pragma unroll
    for (int i = 0; i < 4; ++i)
        #pragma unroll
        for (int j = 0; j < 4; ++j)
            #pragma unroll
            for (int r = 0; r < 4; ++r) acc[i][j][r] = 0.f;

    int steps = K >> 6;
    for (int s = 0; s < steps; ++s) {
        #pragma unroll
        for (int q = 0; q < 2; ++q) {
            gld16(gA[0] + q * 32, dA[0] + q * 4096);
            gld16(gA[1] + q * 32, dA[1] + q * 4096);
            gld16(gB[0] + q * 32, dB[0] + q * 4096);
            gld16(gB[1] + q * 32, dB[1] + q * 4096);
        }
        gA[0] += 64; gA[1] += 64; gB[0] += 64; gB[1] += 64;
        __syncthreads();
        #pragma unroll
        for (int q = 0; q < 2; ++q) {
            short8 a[4], b[4];
            #pragma unroll
            for (int i = 0; i < 4; ++i) a[i] = *(const short8*)(fA[i] + q * 4096);
            #pragma unroll
            for (int j = 0; j < 4; ++j) b[j] = *(const short8*)(fB[j] + q * 4096);
            #pragma unroll
            for (int i = 0; i < 4; ++i)
                #pragma unroll
                for (int j = 0; j < 4; ++j)
                    acc[i][j] = __builtin_amdgcn_mfma_f32_16x16x32_bf16(a[i], b[j], acc[i][j], 0, 0, 0);
        }
        __syncthreads();
    }

    if (kind) {
        #pragma unroll
        for (int i = 0; i < 4; ++i)
            #pragma unroll
            for (int j = 0; j < 4; ++j)
                #pragma unroll
                for (int r = 0; r < 4; ++r) {
                    int row = mt * 128 + wr * 64 + i * 16 + quad * 4 + r;
                    int col = nb * 128 + wc * 64 + j * 16 + l15;
                    out[(size_t)row * H_DIM + col] = acc[i][j][r];
                }
    } else {
        #pragma unroll
        for (int i = 0; i < 4; ++i)
            #pragma unroll
            for (int r = 0; r < 4; ++r) {
                int row = wr * 64 + i * 16 + quad * 4 + r;
                int p = mt * 128 + row;
                if (p < c) {
                    int ent = elist[e * T_TOK + p];
                    int t = ent >> 1, sl = ent & 1;
                    float wt = topkw[t * 2 + sl];
                    u16* yb = sl ? y1 : y0;
                    #pragma unroll
                    for (int j = 0; j < 4; ++j) {
                        int col = nb * 128 + wc * 64 + j * 16 + l15;
                        yb[(size_t)t * H_DIM + col] = f2bf(wt * acc[i][j][r]);
                    }
                }
            }
    }
}

// ---------------------------------------------------------------------------
// The cooperative mega-kernel: all phases, grid.sync() between them.
// ---------------------------------------------------------------------------
__global__ __launch_bounds__(256, 3)
void k_moe(const float* x, const float* rw,
           const float* wg, const float* wu, const float* wd,
           const float* sg, const float* su, const float* sd,
           u16* wgt, u16* wut, u16* sgt, u16* sut, u16* wdt, u16* sdt,
           u16* xb, float* topkw, int* elist, int* cnt,
           u16* act, u16* sact, u16* y0, u16* y1, float* out)
{
    cg::grid_group grid = cg::this_grid();
    __shared__ u16 smem[16384];   // 32 KB, shared by all phases
    int G = gridDim.x;

    // ---- phase 0: zero routing counters ----
    if (blockIdx.x == 0)
        for (int i = threadIdx.x; i < E_NUM * CSTR; i += 256) cnt[i] = 0;
    grid.sync();

    // ---- phase 1: router + all weight transposes ----
    for (int vb = blockIdx.x; vb < P_END; vb += G) {
        prep_vb(vb, smem, x, rw, wg, wu, sg, su, wd, sd,
                wgt, wut, sgt, sut, wdt, sdt, xb, topkw, elist, cnt);
        __syncthreads();   // LDS tile reuse across virtual blocks
    }
    grid.sync();

    // ---- phase 2: gate/up GEMM (XCD-chunked virtual order) ----
    for (int vb0 = blockIdx.x; vb0 < G_GEMM; vb0 += G) {
        int vb = (vb0 & 7) * (G_GEMM / 8) + (vb0 >> 3);
        gateup_vb(vb, smem, xb, wgt, wut, sgt, sut, elist, cnt, act, sact);
    }
    grid.sync();

    // ---- phase 3: down GEMM ----
    for (int vb0 = blockIdx.x; vb0 < D_GRID; vb0 += G) {
        int vb = (vb0 & 7) * (D_GRID / 8) + (vb0 >> 3);
        down_vb(vb, smem, act, sact, wdt, sdt, elist, cnt, topkw, y0, y1, out);
    }
    grid.sync();

    // ---- phase 4: final combine out += y0 + y1 ----
    int n4 = T_TOK * H_DIM / 4;
    for (int i = blockIdx.x * 256 + threadIdx.x; i < n4; i += G * 256) {
        float4 o = ((const float4*)out)[i];
        uint2 a = ((const uint2*)y0)[i];
        uint2 b = ((const uint2*)y1)[i];
        const u16* pa = (const u16*)&a;
        const u16* pb = (const u16*)&b;
        o.x += bf2f(pa[0]) + bf2f(pb[0]);
        o.y += bf2f(pa[1]) + bf2f(pb[1]);
        o.z += bf2f(pa[2]) + bf2f(pb[2]);
        o.w += bf2f(pa[3]) + bf2f(pb[3]);
        ((float4*)out)[i] = o;
    }
}

// ---------------------------------------------------------------------------
extern "C" void kernel_launch(void* const* d_in, const int* in_sizes, int n_in,
                              void* d_out, int out_size, void* d_ws, size_t ws_size,
                              hipStream_t stream)
{
    const float* x  = (const float*)d_in[0];
    const float* rw = (const float*)d_in[1];
    const float* wg = (const float*)d_in[2];
    const float* wu = (const float*)d_in[3];
    const float* wd = (const float*)d_in[4];
    const float* sg = (const float*)d_in[5];
    const float* su = (const float*)d_in[6];
    const float* sd = (const float*)d_in[7];
    float* out = (float*)d_out;

    char* ws = (char*)d_ws;
    const size_t MB = 1024ull * 1024ull;
    u16* wgt  = (u16*)(ws);            // [E][I][H] bf16  16 MB
    u16* wut  = (u16*)(ws + 16 * MB);  // [E][I][H]       16 MB
    u16* wdt  = (u16*)(ws + 32 * MB);  // [E][H][I]       16 MB
    u16* sgt  = (u16*)(ws + 48 * MB);  // [IS][H]          2 MB
    u16* sut  = (u16*)(ws + 50 * MB);  // [IS][H]          2 MB
    u16* sdt  = (u16*)(ws + 52 * MB);  // [H][IS]          2 MB
    u16* xb   = (u16*)(ws + 54 * MB);  // [T][H] bf16      8 MB
    u16* act  = (u16*)(ws + 62 * MB);  // [<=10240][I]    10 MB (128-padded rows)
    u16* sact = (u16*)(ws + 72 * MB);  // [T][IS]          8 MB
    u16* y0   = (u16*)(ws + 80 * MB);  // [T][H] slot0     8 MB
    u16* y1   = (u16*)(ws + 88 * MB);  // [T][H] slot1     8 MB
    float* topkw = (float*)(ws + 96 * MB);             // [T][2]
    int* elist   = (int*)(ws + 96 * MB + 64 * 1024);   // [E][T]
    int* cnt     = (int*)(ws + 97 * MB);               // [E] stride CSTR

    static int gridBlocks = 0;
    if (gridBlocks == 0) {
        int nb = 0;
        hipOccupancyMaxActiveBlocksPerMultiprocessor(&nb, k_moe, 256, 0);
        if (nb < 1) nb = 1;
        if (nb > 8) nb = 8;
        gridBlocks = nb * 256;       // 256 CUs on MI355X
    }

    void* args[] = { (void*)&x, (void*)&rw, (void*)&wg, (void*)&wu, (void*)&wd,
                     (void*)&sg, (void*)&su, (void*)&sd,
                     (void*)&wgt, (void*)&wut, (void*)&sgt, (void*)&sut,
                     (void*)&wdt, (void*)&sdt,
                     (void*)&xb, (void*)&topkw, (void*)&elist, (void*)&cnt,
                     (void*)&act, (void*)&sact, (void*)&y0, (void*)&y1,
                     (void*)&out };
    hipLaunchCooperativeKernel((void*)k_moe, dim3(gridBlocks), dim3(256),
                               args, 0, stream);
}

// Round 17
// 313.137 us; speedup vs baseline: 2.7377x; 2.7377x over previous
//
#include <hip/hip_runtime.h>
#include <hip/hip_bf16.h>
#include <math.h>

// SigmaMoE R24: T=4096, H=1024, I=512, E=16, top-2, IS=1024.
// R16 post-mortem: cooperative mega-kernel catastrophically regressed (857us:
// grid.sync + static partition + L2-locality loss). All three cross-phase
// fusion schemes (launch-split R8, spin R13, cooperative R16) lose — the
// 5-dispatch structure is the measured optimum. Reverted to R22 (264.5 best).
// Single lever: k_prep (256,6)->(256,8). prep is latency-bound (VALU 8%,
// HBM 27%, occ 53%) with VGPR=36<=64 -> HW allows 8 waves/SIMD; only the
// launch-bounds declaration caps it. Pure TLP raise on the top dispatch.
#define H_DIM 1024
#define I_DIM 512
#define E_NUM 16
#define T_TOK 4096
#define IS_DIM 1024
#define CSTR 32       // cnt stride in ints (128B = own cache line per expert)

// k_prep block ranges: router, then ALL weight transposes.
#define P_RT   1024               // router blocks (4 tokens each)
#define P_WU   (P_RT + 2048)      // wg transpose
#define P_SG   (P_WU + 2048)      // wu transpose
#define P_SU   (P_SG + 256)       // sg transpose
#define P_WD   (P_SU + 256)       // su transpose
#define P_SD   (P_WD + 2048)      // wd transpose
#define P_END  (P_SD + 256)       // sd transpose

#define G_GEMM 1152               // pure GEMM: 512 shared + <=640 routed
#define D_GRID 896                // 256 shared + <=640 routed

typedef unsigned short u16;
typedef __attribute__((ext_vector_type(8))) short short8;   // 8 x bf16 (16B)
typedef __attribute__((ext_vector_type(4))) float floatx4;  // 16x16 acc

__device__ __forceinline__ float bf2f(u16 u) {
    union { unsigned int u; float f; } c; c.u = ((unsigned int)u) << 16; return c.f;
}
__device__ __forceinline__ u16 f2bf(float f) {
    union { __hip_bfloat16 b; u16 u; } c;
    c.b = __float2bfloat16(f);
    return c.u;
}
// async global->LDS, 16B/lane; LDS dest = wave-uniform base + lane*16.
__device__ __forceinline__ void gld16(const u16* g, u16* l) {
    __builtin_amdgcn_global_load_lds(
        (const __attribute__((address_space(1))) unsigned int*)g,
        (__attribute__((address_space(3))) unsigned int*)l, 16, 0, 0);
}

// ---------------------------------------------------------------------------
// 64x64 convert+transpose tile (R18): f32 K-major -> bf16 N-major.
// tile = 64 x 72 u16, swizzle (r,c) -> tile[r*72 + (((c>>4)^(r>>4))<<4)+(c&15)]
// writes 2x short8, reads conflict-free.
// ---------------------------------------------------------------------------
__device__ __forceinline__ void tr64(const float* src, u16* dst, int R, int C,
                                     int local, u16* tile)
{
    int tpm = (R >> 6) * (C >> 6);
    int mat = local / tpm;
    int tl_ = local - mat * tpm;
    int tcn = C >> 6;
    int tr = tl_ / tcn, tc = tl_ - tr * tcn;
    src += (size_t)mat * R * C;
    dst += (size_t)mat * R * C;
    int t = threadIdx.x;
    int r0 = t >> 2, g0 = t & 3;
    const float* sp = src + (size_t)(tr * 64 + r0) * C + tc * 64 + (g0 << 4);
    u16 cv[16];
    #pragma unroll
    for (int j = 0; j < 16; j += 4) {
        float4 v = *(const float4*)(sp + j);
        cv[j + 0] = f2bf(v.x);
        cv[j + 1] = f2bf(v.y);
        cv[j + 2] = f2bf(v.z);
        cv[j + 3] = f2bf(v.w);
    }
    u16* tp = tile + r0 * 72 + ((g0 ^ (r0 >> 4)) << 4);
    *(short8*)(tp)     = *(const short8*)(cv);
    *(short8*)(tp + 8) = *(const short8*)(cv + 8);
    __syncthreads();
    int cW = t >> 2, rW = (t & 3) << 4;
    int rb = (((cW >> 4) ^ (t & 3)) << 4) + (cW & 15);
    u16 tmp[16];
    #pragma unroll
    for (int j = 0; j < 16; ++j) tmp[j] = tile[(rW + j) * 72 + rb];
    u16* dp = dst + (size_t)(tc * 64 + cW) * R + tr * 64 + rW;
    *(uint4*)(dp)     = *(const uint4*)(tmp);
    *(uint4*)(dp + 8) = *(const uint4*)(tmp + 8);
}

// ---------------------------------------------------------------------------
// Map a routed block index to (expert, m-tile, sub-tile, act row base).
// ---------------------------------------------------------------------------
__device__ __forceinline__ int derive_routed(int gi, const int* cnt,
                                             int& e, int& mt, int& sub, int& abase)
{
    int off = 0, b = 0;
    #pragma unroll
    for (int ee = 0; ee < E_NUM; ++ee) {
        int mts = (cnt[ee * CSTR] + 127) >> 7;
        int span = mts << 3;
        if (gi < off + span) {
            int local = gi - off;
            e = ee; mt = local >> 3; sub = local & 7; abase = b;
            return 1;
        }
        off += span; b += mts << 7;
    }
    return 0;
}

// ---------------------------------------------------------------------------
// k_prep: router (+ xb emission) and ALL six weight transposes.
// (256,8): latency-bound kernel (VALU 8%, HBM 27%, occ 53% at (256,6));
// VGPR=36<=64 so HW supports 8 waves/SIMD — raise the declared cap.
// ---------------------------------------------------------------------------
__global__ __launch_bounds__(256, 8)
void k_prep(const float* x, const float* rw,
            const float* wg, const float* wu, const float* sg, const float* su,
            const float* wd, const float* sd,
            u16* wgt, u16* wut, u16* sgt, u16* sut, u16* wdt, u16* sdt,
            u16* xb, float* topkw, int* elist, int* cnt)
{
    __shared__ u16 tile[64 * 72];
    int bi = blockIdx.x;
    if (bi >= P_RT) {
        if (bi < P_WU)      tr64(wg, wgt, 1024, 512,  bi - P_RT, tile);
        else if (bi < P_SG) tr64(wu, wut, 1024, 512,  bi - P_WU, tile);
        else if (bi < P_SU) tr64(sg, sgt, 1024, 1024, bi - P_SG, tile);
        else if (bi < P_WD) tr64(su, sut, 1024, 1024, bi - P_SU, tile);
        else if (bi < P_SD) tr64(wd, wdt, 512, 1024,  bi - P_WD, tile);
        else                tr64(sd, sdt, 1024, 1024, bi - P_SD, tile);
        return;
    }
    // ---- router + x->bf16 (4 tokens per block, 1 wave each) ----
    int lane = threadIdx.x & 63;
    int wv = threadIdx.x >> 6;
    int t = bi * 4 + wv;
    const float* xr = x + (size_t)t * H_DIM;
    float xv[16];
    #pragma unroll
    for (int j = 0; j < 16; ++j) xv[j] = xr[j * 64 + lane];
    u16* xrow = xb + (size_t)t * H_DIM;
    #pragma unroll
    for (int j = 0; j < 16; ++j) xrow[j * 64 + lane] = f2bf(xv[j]);
    float sc[E_NUM];
    #pragma unroll
    for (int e = 0; e < E_NUM; ++e) sc[e] = 0.f;
    #pragma unroll
    for (int e = 0; e < E_NUM; ++e) {
        const float* rr = rw + e * H_DIM;
        #pragma unroll
        for (int j = 0; j < 16; ++j) sc[e] += xv[j] * rr[j * 64 + lane];
    }
    #pragma unroll
    for (int off = 32; off > 0; off >>= 1) {
        float tmp[E_NUM];
        #pragma unroll
        for (int e = 0; e < E_NUM; ++e) tmp[e] = __shfl_xor(sc[e], off, 64);
        #pragma unroll
        for (int e = 0; e < E_NUM; ++e) sc[e] += tmp[e];
    }
    if (lane == 0) {
        float b1 = -1e30f, b2 = -1e30f; int i1 = 0, i2 = 0;
        #pragma unroll
        for (int e = 0; e < E_NUM; ++e) {
            if (sc[e] > b1) { b2 = b1; i2 = i1; b1 = sc[e]; i1 = e; }
            else if (sc[e] > b2) { b2 = sc[e]; i2 = e; }
        }
        float w1 = 1.f / (1.f + __expf(b2 - b1));
        float w2 = 1.f - w1;
        topkw[t * 2]     = w1;
        topkw[t * 2 + 1] = w2;
        int p1 = atomicAdd(&cnt[i1 * CSTR], 1); elist[i1 * T_TOK + p1] = (t << 1);
        int p2 = atomicAdd(&cnt[i2 * CSTR], 1); elist[i2 * T_TOK + p2] = (t << 1) | 1;
    }
}

// ---------------------------------------------------------------------------
// Fused gate/up GEMM (routed + shared). Pure GEMM, XCD-chunked swizzle.
// Block = 128 rows x (64 g + 64 u), BK=64, 32KB LDS, (256,3).
// ---------------------------------------------------------------------------
__global__ __launch_bounds__(256, 3)
void k_gateup(const u16* xb, const u16* wgt, const u16* wut,
              const u16* sgt, const u16* sut,
              const int* elist, const int* cnt,
              u16* act, u16* sact)
{
    __shared__ u16 smem[128 * 64 + 64 * 64 + 64 * 64];   // 32 KB
    int bi = blockIdx.x;
    bi = (bi & 7) * (G_GEMM / 8) + (bi >> 3);   // bijective: 1152 % 8 == 0
    int kind, e = 0, mt, cb, abase = 0;
    if (bi < 512) { kind = 1; mt = bi >> 4; cb = bi & 15; }
    else {
        kind = 0;
        if (!derive_routed(bi - 512, cnt, e, mt, cb, abase)) return;
    }

    u16* lA = smem;              // [2 chunks][8 calls][512] = 128x64
    u16* lG = smem + 8192;       // [2][4][512] = 64x64
    u16* lU = smem + 12288;
    int tid = threadIdx.x, lane = tid & 63, w = tid >> 6;
    int srow = lane >> 2, scp = lane & 3;

    const u16* gb = kind ? sgt : (wgt + (size_t)e * I_DIM * H_DIM);
    const u16* ub = kind ? sut : (wut + (size_t)e * I_DIM * H_DIM);
    int c = cnt[e * CSTR];

    const u16 *gA[2], *gG, *gU;
    u16 *dA[2], *dG, *dU;
    #pragma unroll
    for (int jj = 0; jj < 2; ++jj) {
        int call = w * 2 + jj;
        int row = call * 16 + srow;               // 0..127
        int gc = scp ^ ((row >> 1) & 3);
        int tok;
        if (kind) tok = mt * 128 + row;
        else {
            int p = mt * 128 + row;
            int pc = p < c ? p : c - 1;
            tok = elist[e * T_TOK + pc] >> 1;
        }
        gA[jj] = xb + (size_t)tok * H_DIM + gc * 8;
        dA[jj] = lA + call * 512;
    }
    {
        int row = w * 16 + srow;                  // 0..63
        int gc = scp ^ ((row >> 1) & 3);
        gG = gb + (size_t)(cb * 64 + row) * H_DIM + gc * 8;
        gU = ub + (size_t)(cb * 64 + row) * H_DIM + gc * 8;
        dG = lG + w * 512;
        dU = lU + w * 512;
    }

    int wr = w >> 1, wc = w & 1;
    int quad = lane >> 4, l15 = lane & 15;
    const u16 *fA[4], *fG[2], *fU[2];
    #pragma unroll
    for (int i = 0; i < 4; ++i) {
        int r = wr * 64 + i * 16 + l15;
        fA[i] = lA + r * 32 + (quad ^ ((r >> 1) & 3)) * 8;
    }
    #pragma unroll
    for (int j = 0; j < 2; ++j) {
        int n = wc * 32 + j * 16 + l15;
        fG[j] = lG + n * 32 + (quad ^ ((n >> 1) & 3)) * 8;
        fU[j] = lU + n * 32 + (quad ^ ((n >> 1) & 3)) * 8;
    }

    floatx4 accg[4][2], accu[4][2];
    #pragma unroll
    for (int i = 0; i < 4; ++i)
        #pragma unroll
        for (int j = 0; j < 2; ++j)
            #pragma unroll
            for (int r = 0; r < 4; ++r) { accg[i][j][r] = 0.f; accu[i][j][r] = 0.f; }

    for (int s = 0; s < H_DIM / 64; ++s) {
        #pragma unroll
        for (int q = 0; q < 2; ++q) {
            gld16(gA[0] + q * 32, dA[0] + q * 4096);
            gld16(gA[1] + q * 32, dA[1] + q * 4096);
            gld16(gG + q * 32, dG + q * 2048);
            gld16(gU + q * 32, dU + q * 2048);
        }
        gA[0] += 64; gA[1] += 64; gG += 64; gU += 64;
        __syncthreads();
        #pragma unroll
        for (int q = 0; q < 2; ++q) {
            short8 a[4], g[2], u[2];
            #pragma unroll
            for (int i = 0; i < 4; ++i) a[i] = *(const short8*)(fA[i] + q * 4096);
            #pragma unroll
            for (int j = 0; j < 2; ++j) {
                g[j] = *(const short8*)(fG[j] + q * 2048);
                u[j] = *(const short8*)(fU[j] + q * 2048);
            }
            #pragma unroll
            for (int i = 0; i < 4; ++i)
                #pragma unroll
                for (int j = 0; j < 2; ++j) {
                    accg[i][j] = __builtin_amdgcn_mfma_f32_16x16x32_bf16(a[i], g[j], accg[i][j], 0, 0, 0);
                    accu[i][j] = __builtin_amdgcn_mfma_f32_16x16x32_bf16(a[i], u[j], accu[i][j], 0, 0, 0);
                }
        }
        __syncthreads();
    }

    u16* obase = kind ? (sact + (size_t)(mt * 128) * IS_DIM)
                      : (act + (size_t)(abase + mt * 128) * I_DIM);
    int old = kind ? IS_DIM : I_DIM;
    #pragma unroll
    for (int i = 0; i < 4; ++i)
        #pragma unroll
        for (int j = 0; j < 2; ++j)
            #pragma unroll
            for (int r = 0; r < 4; ++r) {
                int row = wr * 64 + i * 16 + quad * 4 + r;
                int col = cb * 64 + wc * 32 + j * 16 + l15;
                float gg = accg[i][j][r], uu = accu[i][j][r];
                float aa = gg / (1.f + __expf(-gg)) * uu;   // silu(g)*u
                obase[(size_t)row * old + col] = f2bf(aa);
            }
}

// ---------------------------------------------------------------------------
// Fused down GEMM. Block = 128 rows x 128 cols, BK=64, 2-phase, 32KB LDS.
// XCD-chunked swizzle (896 % 8 == 0). Routed K=512 -> y0/y1; shared -> out.
// ---------------------------------------------------------------------------
__global__ __launch_bounds__(256, 3)
void k_down(const u16* act, const u16* sact, const u16* wdt, const u16* sdt,
            const int* elist, const int* cnt, const float* topkw,
            u16* y0, u16* y1, float* out)
{
    int bi = blockIdx.x;
    bi = (bi & 7) * (D_GRID / 8) + (bi >> 3);   // bijective: 896 % 8 == 0
    int kind, e = 0, mt, nb, abase = 0;
    if (bi < 256) { kind = 1; mt = bi >> 3; nb = bi & 7; }     // 32 mts x 8 nbs
    else {
        kind = 0;
        if (!derive_routed(bi - 256, cnt, e, mt, nb, abase)) return;
    }

    __shared__ u16 smem[128 * 64 * 2];     // lA + lB, 32 KB
    u16* lA = smem;              // [2][8][512] = 128 x 64
    u16* lB = smem + 8192;       // [2][8][512] = 128 x 64 (B rows = out cols)
    int tid = threadIdx.x, lane = tid & 63, w = tid >> 6;
    int srow = lane >> 2, scp = lane & 3;

    int K = kind ? IS_DIM : I_DIM;
    const u16* ab = kind ? (sact + (size_t)(mt * 128) * IS_DIM)
                         : (act + (size_t)(abase + mt * 128) * I_DIM);
    const u16* bb = kind ? (sdt + (size_t)(nb * 128) * IS_DIM)
                         : (wdt + ((size_t)e * H_DIM + nb * 128) * I_DIM);
    int c = cnt[e * CSTR];

    const u16 *gA[2], *gB[2];
    u16 *dA[2], *dB[2];
    #pragma unroll
    for (int jj = 0; jj < 2; ++jj) {
        int call = w * 2 + jj;
        int row = call * 16 + srow;               // 0..127
        int gc = scp ^ ((row >> 1) & 3);
        gA[jj] = ab + (size_t)row * K + gc * 8;
        dA[jj] = lA + call * 512;
        gB[jj] = bb + (size_t)row * K + gc * 8;
        dB[jj] = lB + call * 512;
    }

    int wr = w >> 1, wc = w & 1;
    int quad = lane >> 4, l15 = lane & 15;
    const u16 *fA[4], *fB[4];
    #pragma unroll
    for (int i = 0; i < 4; ++i) {
        int r = wr * 64 + i * 16 + l15;
        fA[i] = lA + r * 32 + (quad ^ ((r >> 1) & 3)) * 8;
    }
    #pragma unroll
    for (int j = 0; j < 4; ++j) {
        int n = wc * 64 + j * 16 + l15;
        fB[j] = lB + n * 32 + (quad ^ ((n >> 1) & 3)) * 8;
    }

    floatx4 acc[4][4];
    #pragma unroll
    for (int i = 0; i < 4; ++i)
        #pragma unroll
        for (int j = 0; j < 4; ++j)
            #pragma unroll
            for (int r = 0; r < 4; ++r) acc[i][j][r] = 0.f;

    int steps = K >> 6;
    for (int s = 0; s < steps; ++s) {
        #pragma unroll
        for (int q = 0; q < 2; ++q) {
            gld16(gA[0] + q * 32, dA[0] + q * 4096);
            gld16(gA[1] + q * 32, dA[1] + q * 4096);
            gld16(gB[0] + q * 32, dB[0] + q * 4096);
            gld16(gB[1] + q * 32, dB[1] + q * 4096);
        }
        gA[0] += 64; gA[1] += 64; gB[0] += 64; gB[1] += 64;
        __syncthreads();
        #pragma unroll
        for (int q = 0; q < 2; ++q) {
            short8 a[4], b[4];
            #pragma unroll
            for (int i = 0; i < 4; ++i) a[i] = *(const short8*)(fA[i] + q * 4096);
            #pragma unroll
            for (int j = 0; j < 4; ++j) b[j] = *(const short8*)(fB[j] + q * 4096);
            #pragma unroll
            for (int i = 0; i < 4; ++i)
                #pragma unroll
                for (int j = 0; j < 4; ++j)
                    acc[i][j] = __builtin_amdgcn_mfma_f32_16x16x32_bf16(a[i], b[j], acc[i][j], 0, 0, 0);
        }
        __syncthreads();
    }

    if (kind) {
        #pragma unroll
        for (int i = 0; i < 4; ++i)
            #pragma unroll
            for (int j = 0; j < 4; ++j)
                #pragma unroll
                for (int r = 0; r < 4; ++r) {
                    int row = mt * 128 + wr * 64 + i * 16 + quad * 4 + r;
                    int col = nb * 128 + wc * 64 + j * 16 + l15;
                    out[(size_t)row * H_DIM + col] = acc[i][j][r];
                }
    } else {
        #pragma unroll
        for (int i = 0; i < 4; ++i)
            #pragma unroll
            for (int r = 0; r < 4; ++r) {
                int row = wr * 64 + i * 16 + quad * 4 + r;
                int p = mt * 128 + row;
                if (p < c) {
                    int ent = elist[e * T_TOK + p];
                    int t = ent >> 1, sl = ent & 1;
                    float wt = topkw[t * 2 + sl];
                    u16* yb = sl ? y1 : y0;
                    #pragma unroll
                    for (int j = 0; j < 4; ++j) {
                        int col = nb * 128 + wc * 64 + j * 16 + l15;
                        yb[(size_t)t * H_DIM + col] = f2bf(wt * acc[i][j][r]);
                    }
                }
            }
    }
}

// Final combine: out += y0 + y1 (out already holds shared-expert result).
__global__ __launch_bounds__(256)
void k_final(float* out, const u16* y0, const u16* y1)
{
    int i = blockIdx.x * 256 + threadIdx.x;
    float4 o = ((const float4*)out)[i];
    uint2 a = ((const uint2*)y0)[i];
    uint2 b = ((const uint2*)y1)[i];
    const u16* pa = (const u16*)&a;
    const u16* pb = (const u16*)&b;
    o.x += bf2f(pa[0]) + bf2f(pb[0]);
    o.y += bf2f(pa[1]) + bf2f(pb[1]);
    o.z += bf2f(pa[2]) + bf2f(pb[2]);
    o.w += bf2f(pa[3]) + bf2f(pb[3]);
    ((float4*)out)[i] = o;
}

// ---------------------------------------------------------------------------
extern "C" void kernel_launch(void* const* d_in, const int* in_sizes, int n_in,
                              void* d_out, int out_size, void* d_ws, size_t ws_size,
                              hipStream_t stream)
{
    const float* x  = (const float*)d_in[0];
    const float* rw = (const float*)d_in[1];
    const float* wg = (const float*)d_in[2];
    const float* wu = (const float*)d_in[3];
    const float* wd = (const float*)d_in[4];
    const float* sg = (const float*)d_in[5];
    const float* su = (const float*)d_in[6];
    const float* sd = (const float*)d_in[7];
    float* out = (float*)d_out;

    char* ws = (char*)d_ws;
    const size_t MB = 1024ull * 1024ull;
    u16* wgt  = (u16*)(ws);            // [E][I][H] bf16  16 MB
    u16* wut  = (u16*)(ws + 16 * MB);  // [E][I][H]       16 MB
    u16* wdt  = (u16*)(ws + 32 * MB);  // [E][H][I]       16 MB
    u16* sgt  = (u16*)(ws + 48 * MB);  // [IS][H]          2 MB
    u16* sut  = (u16*)(ws + 50 * MB);  // [IS][H]          2 MB
    u16* sdt  = (u16*)(ws + 52 * MB);  // [H][IS]          2 MB
    u16* xb   = (u16*)(ws + 54 * MB);  // [T][H] bf16      8 MB
    u16* act  = (u16*)(ws + 62 * MB);  // [<=10240][I]    10 MB (128-padded rows)
    u16* sact = (u16*)(ws + 72 * MB);  // [T][IS]          8 MB
    u16* y0   = (u16*)(ws + 80 * MB);  // [T][H] slot0     8 MB
    u16* y1   = (u16*)(ws + 88 * MB);  // [T][H] slot1     8 MB
    float* topkw  = (float*)(ws + 96 * MB);            // [T][2]
    int* elist    = (int*)(ws + 96 * MB + 64 * 1024);  // [E][T]
    int* cnt      = (int*)(ws + 97 * MB);              // [E] stride CSTR

    hipMemsetAsync(cnt, 0, E_NUM * CSTR * sizeof(int), stream);
    k_prep<<<P_END, 256, 0, stream>>>(x, rw, wg, wu, sg, su, wd, sd,
                                      wgt, wut, sgt, sut, wdt, sdt,
                                      xb, topkw, elist, cnt);
    k_gateup<<<G_GEMM, 256, 0, stream>>>(xb, wgt, wut, sgt, sut,
                                         elist, cnt, act, sact);
    k_down<<<D_GRID, 256, 0, stream>>>(act, sact, wdt, sdt,
                                       elist, cnt, topkw, y0, y1, out);
    k_final<<<T_TOK * H_DIM / 4 / 256, 256, 0, stream>>>(out, y0, y1);
}

// Round 18
// 263.263 us; speedup vs baseline: 3.2563x; 1.1894x over previous
//
#include <hip/hip_runtime.h>
#include <hip/hip_bf16.h>
#include <math.h>

// SigmaMoE R25 = R22 exactly (best measured: 264.5us).
// R17 post-mortem: (256,8) on prep regressed 61->110us — the tighter
// launch-bounds squeezed regalloc (VGPR 36->28), serializing the load
// stream; per-thread MLP loss > occupancy gain. Reverted to (256,6).
// Census at this config: prep 61 (latency-bound; all 5 levers tried),
// gateup ~50 / down ~40 (2-phase 128-tile structural ceiling at these grid
// sizes), final ~10, launch/ramp overhead resistant to all fusion schemes
// (R8/R13/R16 all regressed). Converged.
#define H_DIM 1024
#define I_DIM 512
#define E_NUM 16
#define T_TOK 4096
#define IS_DIM 1024
#define CSTR 32       // cnt stride in ints (128B = own cache line per expert)

// k_prep block ranges: router, then ALL weight transposes.
#define P_RT   1024               // router blocks (4 tokens each)
#define P_WU   (P_RT + 2048)      // wg transpose
#define P_SG   (P_WU + 2048)      // wu transpose
#define P_SU   (P_SG + 256)       // sg transpose
#define P_WD   (P_SU + 256)       // su transpose
#define P_SD   (P_WD + 2048)      // wd transpose
#define P_END  (P_SD + 256)       // sd transpose

#define G_GEMM 1152               // pure GEMM: 512 shared + <=640 routed
#define D_GRID 896                // 256 shared + <=640 routed

typedef unsigned short u16;
typedef __attribute__((ext_vector_type(8))) short short8;   // 8 x bf16 (16B)
typedef __attribute__((ext_vector_type(4))) float floatx4;  // 16x16 acc

__device__ __forceinline__ float bf2f(u16 u) {
    union { unsigned int u; float f; } c; c.u = ((unsigned int)u) << 16; return c.f;
}
__device__ __forceinline__ u16 f2bf(float f) {
    union { __hip_bfloat16 b; u16 u; } c;
    c.b = __float2bfloat16(f);
    return c.u;
}
// async global->LDS, 16B/lane; LDS dest = wave-uniform base + lane*16.
__device__ __forceinline__ void gld16(const u16* g, u16* l) {
    __builtin_amdgcn_global_load_lds(
        (const __attribute__((address_space(1))) unsigned int*)g,
        (__attribute__((address_space(3))) unsigned int*)l, 16, 0, 0);
}

// ---------------------------------------------------------------------------
// 64x64 convert+transpose tile (R18): f32 K-major -> bf16 N-major.
// tile = 64 x 72 u16, swizzle (r,c) -> tile[r*72 + (((c>>4)^(r>>4))<<4)+(c&15)]
// writes 2x short8, reads conflict-free.
// ---------------------------------------------------------------------------
__device__ __forceinline__ void tr64(const float* src, u16* dst, int R, int C,
                                     int local, u16* tile)
{
    int tpm = (R >> 6) * (C >> 6);
    int mat = local / tpm;
    int tl_ = local - mat * tpm;
    int tcn = C >> 6;
    int tr = tl_ / tcn, tc = tl_ - tr * tcn;
    src += (size_t)mat * R * C;
    dst += (size_t)mat * R * C;
    int t = threadIdx.x;
    int r0 = t >> 2, g0 = t & 3;
    const float* sp = src + (size_t)(tr * 64 + r0) * C + tc * 64 + (g0 << 4);
    u16 cv[16];
    #pragma unroll
    for (int j = 0; j < 16; j += 4) {
        float4 v = *(const float4*)(sp + j);
        cv[j + 0] = f2bf(v.x);
        cv[j + 1] = f2bf(v.y);
        cv[j + 2] = f2bf(v.z);
        cv[j + 3] = f2bf(v.w);
    }
    u16* tp = tile + r0 * 72 + ((g0 ^ (r0 >> 4)) << 4);
    *(short8*)(tp)     = *(const short8*)(cv);
    *(short8*)(tp + 8) = *(const short8*)(cv + 8);
    __syncthreads();
    int cW = t >> 2, rW = (t & 3) << 4;
    int rb = (((cW >> 4) ^ (t & 3)) << 4) + (cW & 15);
    u16 tmp[16];
    #pragma unroll
    for (int j = 0; j < 16; ++j) tmp[j] = tile[(rW + j) * 72 + rb];
    u16* dp = dst + (size_t)(tc * 64 + cW) * R + tr * 64 + rW;
    *(uint4*)(dp)     = *(const uint4*)(tmp);
    *(uint4*)(dp + 8) = *(const uint4*)(tmp + 8);
}

// ---------------------------------------------------------------------------
// Map a routed block index to (expert, m-tile, sub-tile, act row base).
// ---------------------------------------------------------------------------
__device__ __forceinline__ int derive_routed(int gi, const int* cnt,
                                             int& e, int& mt, int& sub, int& abase)
{
    int off = 0, b = 0;
    #pragma unroll
    for (int ee = 0; ee < E_NUM; ++ee) {
        int mts = (cnt[ee * CSTR] + 127) >> 7;
        int span = mts << 3;
        if (gi < off + span) {
            int local = gi - off;
            e = ee; mt = local >> 3; sub = local & 7; abase = b;
            return 1;
        }
        off += span; b += mts << 7;
    }
    return 0;
}

// ---------------------------------------------------------------------------
// k_prep: router (+ xb emission) and ALL six weight transposes. (256,6).
// ---------------------------------------------------------------------------
__global__ __launch_bounds__(256, 6)
void k_prep(const float* x, const float* rw,
            const float* wg, const float* wu, const float* sg, const float* su,
            const float* wd, const float* sd,
            u16* wgt, u16* wut, u16* sgt, u16* sut, u16* wdt, u16* sdt,
            u16* xb, float* topkw, int* elist, int* cnt)
{
    __shared__ u16 tile[64 * 72];
    int bi = blockIdx.x;
    if (bi >= P_RT) {
        if (bi < P_WU)      tr64(wg, wgt, 1024, 512,  bi - P_RT, tile);
        else if (bi < P_SG) tr64(wu, wut, 1024, 512,  bi - P_WU, tile);
        else if (bi < P_SU) tr64(sg, sgt, 1024, 1024, bi - P_SG, tile);
        else if (bi < P_WD) tr64(su, sut, 1024, 1024, bi - P_SU, tile);
        else if (bi < P_SD) tr64(wd, wdt, 512, 1024,  bi - P_WD, tile);
        else                tr64(sd, sdt, 1024, 1024, bi - P_SD, tile);
        return;
    }
    // ---- router + x->bf16 (4 tokens per block, 1 wave each) ----
    int lane = threadIdx.x & 63;
    int wv = threadIdx.x >> 6;
    int t = bi * 4 + wv;
    const float* xr = x + (size_t)t * H_DIM;
    float xv[16];
    #pragma unroll
    for (int j = 0; j < 16; ++j) xv[j] = xr[j * 64 + lane];
    u16* xrow = xb + (size_t)t * H_DIM;
    #pragma unroll
    for (int j = 0; j < 16; ++j) xrow[j * 64 + lane] = f2bf(xv[j]);
    float sc[E_NUM];
    #pragma unroll
    for (int e = 0; e < E_NUM; ++e) sc[e] = 0.f;
    #pragma unroll
    for (int e = 0; e < E_NUM; ++e) {
        const float* rr = rw + e * H_DIM;
        #pragma unroll
        for (int j = 0; j < 16; ++j) sc[e] += xv[j] * rr[j * 64 + lane];
    }
    #pragma unroll
    for (int off = 32; off > 0; off >>= 1) {
        float tmp[E_NUM];
        #pragma unroll
        for (int e = 0; e < E_NUM; ++e) tmp[e] = __shfl_xor(sc[e], off, 64);
        #pragma unroll
        for (int e = 0; e < E_NUM; ++e) sc[e] += tmp[e];
    }
    if (lane == 0) {
        float b1 = -1e30f, b2 = -1e30f; int i1 = 0, i2 = 0;
        #pragma unroll
        for (int e = 0; e < E_NUM; ++e) {
            if (sc[e] > b1) { b2 = b1; i2 = i1; b1 = sc[e]; i1 = e; }
            else if (sc[e] > b2) { b2 = sc[e]; i2 = e; }
        }
        float w1 = 1.f / (1.f + __expf(b2 - b1));
        float w2 = 1.f - w1;
        topkw[t * 2]     = w1;
        topkw[t * 2 + 1] = w2;
        int p1 = atomicAdd(&cnt[i1 * CSTR], 1); elist[i1 * T_TOK + p1] = (t << 1);
        int p2 = atomicAdd(&cnt[i2 * CSTR], 1); elist[i2 * T_TOK + p2] = (t << 1) | 1;
    }
}

// ---------------------------------------------------------------------------
// Fused gate/up GEMM (routed + shared). Pure GEMM, XCD-chunked swizzle.
// Block = 128 rows x (64 g + 64 u), BK=64, 32KB LDS, (256,3).
// ---------------------------------------------------------------------------
__global__ __launch_bounds__(256, 3)
void k_gateup(const u16* xb, const u16* wgt, const u16* wut,
              const u16* sgt, const u16* sut,
              const int* elist, const int* cnt,
              u16* act, u16* sact)
{
    __shared__ u16 smem[128 * 64 + 64 * 64 + 64 * 64];   // 32 KB
    int bi = blockIdx.x;
    bi = (bi & 7) * (G_GEMM / 8) + (bi >> 3);   // bijective: 1152 % 8 == 0
    int kind, e = 0, mt, cb, abase = 0;
    if (bi < 512) { kind = 1; mt = bi >> 4; cb = bi & 15; }
    else {
        kind = 0;
        if (!derive_routed(bi - 512, cnt, e, mt, cb, abase)) return;
    }

    u16* lA = smem;              // [2 chunks][8 calls][512] = 128x64
    u16* lG = smem + 8192;       // [2][4][512] = 64x64
    u16* lU = smem + 12288;
    int tid = threadIdx.x, lane = tid & 63, w = tid >> 6;
    int srow = lane >> 2, scp = lane & 3;

    const u16* gb = kind ? sgt : (wgt + (size_t)e * I_DIM * H_DIM);
    const u16* ub = kind ? sut : (wut + (size_t)e * I_DIM * H_DIM);
    int c = cnt[e * CSTR];

    const u16 *gA[2], *gG, *gU;
    u16 *dA[2], *dG, *dU;
    #pragma unroll
    for (int jj = 0; jj < 2; ++jj) {
        int call = w * 2 + jj;
        int row = call * 16 + srow;               // 0..127
        int gc = scp ^ ((row >> 1) & 3);
        int tok;
        if (kind) tok = mt * 128 + row;
        else {
            int p = mt * 128 + row;
            int pc = p < c ? p : c - 1;
            tok = elist[e * T_TOK + pc] >> 1;
        }
        gA[jj] = xb + (size_t)tok * H_DIM + gc * 8;
        dA[jj] = lA + call * 512;
    }
    {
        int row = w * 16 + srow;                  // 0..63
        int gc = scp ^ ((row >> 1) & 3);
        gG = gb + (size_t)(cb * 64 + row) * H_DIM + gc * 8;
        gU = ub + (size_t)(cb * 64 + row) * H_DIM + gc * 8;
        dG = lG + w * 512;
        dU = lU + w * 512;
    }

    int wr = w >> 1, wc = w & 1;
    int quad = lane >> 4, l15 = lane & 15;
    const u16 *fA[4], *fG[2], *fU[2];
    #pragma unroll
    for (int i = 0; i < 4; ++i) {
        int r = wr * 64 + i * 16 + l15;
        fA[i] = lA + r * 32 + (quad ^ ((r >> 1) & 3)) * 8;
    }
    #pragma unroll
    for (int j = 0; j < 2; ++j) {
        int n = wc * 32 + j * 16 + l15;
        fG[j] = lG + n * 32 + (quad ^ ((n >> 1) & 3)) * 8;
        fU[j] = lU + n * 32 + (quad ^ ((n >> 1) & 3)) * 8;
    }

    floatx4 accg[4][2], accu[4][2];
    #pragma unroll
    for (int i = 0; i < 4; ++i)
        #pragma unroll
        for (int j = 0; j < 2; ++j)
            #pragma unroll
            for (int r = 0; r < 4; ++r) { accg[i][j][r] = 0.f; accu[i][j][r] = 0.f; }

    for (int s = 0; s < H_DIM / 64; ++s) {
        #pragma unroll
        for (int q = 0; q < 2; ++q) {
            gld16(gA[0] + q * 32, dA[0] + q * 4096);
            gld16(gA[1] + q * 32, dA[1] + q * 4096);
            gld16(gG + q * 32, dG + q * 2048);
            gld16(gU + q * 32, dU + q * 2048);
        }
        gA[0] += 64; gA[1] += 64; gG += 64; gU += 64;
        __syncthreads();
        #pragma unroll
        for (int q = 0; q < 2; ++q) {
            short8 a[4], g[2], u[2];
            #pragma unroll
            for (int i = 0; i < 4; ++i) a[i] = *(const short8*)(fA[i] + q * 4096);
            #pragma unroll
            for (int j = 0; j < 2; ++j) {
                g[j] = *(const short8*)(fG[j] + q * 2048);
                u[j] = *(const short8*)(fU[j] + q * 2048);
            }
            #pragma unroll
            for (int i = 0; i < 4; ++i)
                #pragma unroll
                for (int j = 0; j < 2; ++j) {
                    accg[i][j] = __builtin_amdgcn_mfma_f32_16x16x32_bf16(a[i], g[j], accg[i][j], 0, 0, 0);
                    accu[i][j] = __builtin_amdgcn_mfma_f32_16x16x32_bf16(a[i], u[j], accu[i][j], 0, 0, 0);
                }
        }
        __syncthreads();
    }

    u16* obase = kind ? (sact + (size_t)(mt * 128) * IS_DIM)
                      : (act + (size_t)(abase + mt * 128) * I_DIM);
    int old = kind ? IS_DIM : I_DIM;
    #pragma unroll
    for (int i = 0; i < 4; ++i)
        #pragma unroll
        for (int j = 0; j < 2; ++j)
            #pragma unroll
            for (int r = 0; r < 4; ++r) {
                int row = wr * 64 + i * 16 + quad * 4 + r;
                int col = cb * 64 + wc * 32 + j * 16 + l15;
                float gg = accg[i][j][r], uu = accu[i][j][r];
                float aa = gg / (1.f + __expf(-gg)) * uu;   // silu(g)*u
                obase[(size_t)row * old + col] = f2bf(aa);
            }
}

// ---------------------------------------------------------------------------
// Fused down GEMM. Block = 128 rows x 128 cols, BK=64, 2-phase, 32KB LDS.
// XCD-chunked swizzle (896 % 8 == 0). Routed K=512 -> y0/y1; shared -> out.
// ---------------------------------------------------------------------------
__global__ __launch_bounds__(256, 3)
void k_down(const u16* act, const u16* sact, const u16* wdt, const u16* sdt,
            const int* elist, const int* cnt, const float* topkw,
            u16* y0, u16* y1, float* out)
{
    int bi = blockIdx.x;
    bi = (bi & 7) * (D_GRID / 8) + (bi >> 3);   // bijective: 896 % 8 == 0
    int kind, e = 0, mt, nb, abase = 0;
    if (bi < 256) { kind = 1; mt = bi >> 3; nb = bi & 7; }     // 32 mts x 8 nbs
    else {
        kind = 0;
        if (!derive_routed(bi - 256, cnt, e, mt, nb, abase)) return;
    }

    __shared__ u16 smem[128 * 64 * 2];     // lA + lB, 32 KB
    u16* lA = smem;              // [2][8][512] = 128 x 64
    u16* lB = smem + 8192;       // [2][8][512] = 128 x 64 (B rows = out cols)
    int tid = threadIdx.x, lane = tid & 63, w = tid >> 6;
    int srow = lane >> 2, scp = lane & 3;

    int K = kind ? IS_DIM : I_DIM;
    const u16* ab = kind ? (sact + (size_t)(mt * 128) * IS_DIM)
                         : (act + (size_t)(abase + mt * 128) * I_DIM);
    const u16* bb = kind ? (sdt + (size_t)(nb * 128) * IS_DIM)
                         : (wdt + ((size_t)e * H_DIM + nb * 128) * I_DIM);
    int c = cnt[e * CSTR];

    const u16 *gA[2], *gB[2];
    u16 *dA[2], *dB[2];
    #pragma unroll
    for (int jj = 0; jj < 2; ++jj) {
        int call = w * 2 + jj;
        int row = call * 16 + srow;               // 0..127
        int gc = scp ^ ((row >> 1) & 3);
        gA[jj] = ab + (size_t)row * K + gc * 8;
        dA[jj] = lA + call * 512;
        gB[jj] = bb + (size_t)row * K + gc * 8;
        dB[jj] = lB + call * 512;
    }

    int wr = w >> 1, wc = w & 1;
    int quad = lane >> 4, l15 = lane & 15;
    const u16 *fA[4], *fB[4];
    #pragma unroll
    for (int i = 0; i < 4; ++i) {
        int r = wr * 64 + i * 16 + l15;
        fA[i] = lA + r * 32 + (quad ^ ((r >> 1) & 3)) * 8;
    }
    #pragma unroll
    for (int j = 0; j < 4; ++j) {
        int n = wc * 64 + j * 16 + l15;
        fB[j] = lB + n * 32 + (quad ^ ((n >> 1) & 3)) * 8;
    }

    floatx4 acc[4][4];
    #pragma unroll
    for (int i = 0; i < 4; ++i)
        #pragma unroll
        for (int j = 0; j < 4; ++j)
            #pragma unroll
            for (int r = 0; r < 4; ++r) acc[i][j][r] = 0.f;

    int steps = K >> 6;
    for (int s = 0; s < steps; ++s) {
        #pragma unroll
        for (int q = 0; q < 2; ++q) {
            gld16(gA[0] + q * 32, dA[0] + q * 4096);
            gld16(gA[1] + q * 32, dA[1] + q * 4096);
            gld16(gB[0] + q * 32, dB[0] + q * 4096);
            gld16(gB[1] + q * 32, dB[1] + q * 4096);
        }
        gA[0] += 64; gA[1] += 64; gB[0] += 64; gB[1] += 64;
        __syncthreads();
        #pragma unroll
        for (int q = 0; q < 2; ++q) {
            short8 a[4], b[4];
            #pragma unroll
            for (int i = 0; i < 4; ++i) a[i] = *(const short8*)(fA[i] + q * 4096);
            #pragma unroll
            for (int j = 0; j < 4; ++j) b[j] = *(const short8*)(fB[j] + q * 4096);
            #pragma unroll
            for (int i = 0; i < 4; ++i)
                #pragma unroll
                for (int j = 0; j < 4; ++j)
                    acc[i][j] = __builtin_amdgcn_mfma_f32_16x16x32_bf16(a[i], b[j], acc[i][j], 0, 0, 0);
        }
        __syncthreads();
    }

    if (kind) {
        #pragma unroll
        for (int i = 0; i < 4; ++i)
            #pragma unroll
            for (int j = 0; j < 4; ++j)
                #pragma unroll
                for (int r = 0; r < 4; ++r) {
                    int row = mt * 128 + wr * 64 + i * 16 + quad * 4 + r;
                    int col = nb * 128 + wc * 64 + j * 16 + l15;
                    out[(size_t)row * H_DIM + col] = acc[i][j][r];
                }
    } else {
        #pragma unroll
        for (int i = 0; i < 4; ++i)
            #pragma unroll
            for (int r = 0; r < 4; ++r) {
                int row = wr * 64 + i * 16 + quad * 4 + r;
                int p = mt * 128 + row;
                if (p < c) {
                    int ent = elist[e * T_TOK + p];
                    int t = ent >> 1, sl = ent & 1;
                    float wt = topkw[t * 2 + sl];
                    u16* yb = sl ? y1 : y0;
                    #pragma unroll
                    for (int j = 0; j < 4; ++j) {
                        int col = nb * 128 + wc * 64 + j * 16 + l15;
                        yb[(size_t)t * H_DIM + col] = f2bf(wt * acc[i][j][r]);
                    }
                }
            }
    }
}

// Final combine: out += y0 + y1 (out already holds shared-expert result).
__global__ __launch_bounds__(256)
void k_final(float* out, const u16* y0, const u16* y1)
{
    int i = blockIdx.x * 256 + threadIdx.x;
    float4 o = ((const float4*)out)[i];
    uint2 a = ((const uint2*)y0)[i];
    uint2 b = ((const uint2*)y1)[i];
    const u16* pa = (const u16*)&a;
    const u16* pb = (const u16*)&b;
    o.x += bf2f(pa[0]) + bf2f(pb[0]);
    o.y += bf2f(pa[1]) + bf2f(pb[1]);
    o.z += bf2f(pa[2]) + bf2f(pb[2]);
    o.w += bf2f(pa[3]) + bf2f(pb[3]);
    ((float4*)out)[i] = o;
}

// ---------------------------------------------------------------------------
extern "C" void kernel_launch(void* const* d_in, const int* in_sizes, int n_in,
                              void* d_out, int out_size, void* d_ws, size_t ws_size,
                              hipStream_t stream)
{
    const float* x  = (const float*)d_in[0];
    const float* rw = (const float*)d_in[1];
    const float* wg = (const float*)d_in[2];
    const float* wu = (const float*)d_in[3];
    const float* wd = (const float*)d_in[4];
    const float* sg = (const float*)d_in[5];
    const float* su = (const float*)d_in[6];
    const float* sd = (const float*)d_in[7];
    float* out = (float*)d_out;

    char* ws = (char*)d_ws;
    const size_t MB = 1024ull * 1024ull;
    u16* wgt  = (u16*)(ws);            // [E][I][H] bf16  16 MB
    u16* wut  = (u16*)(ws + 16 * MB);  // [E][I][H]       16 MB
    u16* wdt  = (u16*)(ws + 32 * MB);  // [E][H][I]       16 MB
    u16* sgt  = (u16*)(ws + 48 * MB);  // [IS][H]          2 MB
    u16* sut  = (u16*)(ws + 50 * MB);  // [IS][H]          2 MB
    u16* sdt  = (u16*)(ws + 52 * MB);  // [H][IS]          2 MB
    u16* xb   = (u16*)(ws + 54 * MB);  // [T][H] bf16      8 MB
    u16* act  = (u16*)(ws + 62 * MB);  // [<=10240][I]    10 MB (128-padded rows)
    u16* sact = (u16*)(ws + 72 * MB);  // [T][IS]          8 MB
    u16* y0   = (u16*)(ws + 80 * MB);  // [T][H] slot0     8 MB
    u16* y1   = (u16*)(ws + 88 * MB);  // [T][H] slot1     8 MB
    float* topkw  = (float*)(ws + 96 * MB);            // [T][2]
    int* elist    = (int*)(ws + 96 * MB + 64 * 1024);  // [E][T]
    int* cnt      = (int*)(ws + 97 * MB);              // [E] stride CSTR

    hipMemsetAsync(cnt, 0, E_NUM * CSTR * sizeof(int), stream);
    k_prep<<<P_END, 256, 0, stream>>>(x, rw, wg, wu, sg, su, wd, sd,
                                      wgt, wut, sgt, sut, wdt, sdt,
                                      xb, topkw, elist, cnt);
    k_gateup<<<G_GEMM, 256, 0, stream>>>(xb, wgt, wut, sgt, sut,
                                         elist, cnt, act, sact);
    k_down<<<D_GRID, 256, 0, stream>>>(act, sact, wdt, sdt,
                                       elist, cnt, topkw, y0, y1, out);
    k_final<<<T_TOK * H_DIM / 4 / 256, 256, 0, stream>>>(out, y0, y1);
}